// Round 4
// baseline (144.701 us; speedup 1.0000x reference)
//
#include <hip/hip_runtime.h>
#include <float.h>

// Batched 1D linear interpolation with clamped extrapolation.
// t: [B,N] sorted fp32, v: [B,N] fp32, r: [B,M] fp32 -> out: [B,M] fp32
constexpr int B = 2048;
constexpr int N = 4096;
constexpr int M = 4096;
constexpr int K = 4088;  // LDS: st (N+4)*4 + sv N*4 + lut K*2 = 16400+16384+8176 = 40960 B
constexpr int T = 512;   // 4 blocks/CU x 8 waves = 32 waves/CU
constexpr int BPB = 2;   // batches per block: pipeline stage(i+1) under queries(i)
constexpr int GRID = B / BPB;  // 1024 = 256 CUs x 4 resident blocks, single dispatch round

__global__ __launch_bounds__(T, 8) void interp_kernel(
    const float* __restrict__ t,
    const float* __restrict__ v,
    const float* __restrict__ r,
    float* __restrict__ out) {
    __shared__ __align__(16) float st[N + 4];       // st[N..N+3] = +inf sentinels
    __shared__ __align__(16) float sv[N];
    __shared__ unsigned short lut[K];               // lut[k] = first j with (int)(t[j]*K) >= k; else N

    const int tid = threadIdx.x;
    const int b0 = blockIdx.x * BPB;

    // Prefetch registers for the upcoming batch's t/v: 64 B/thread = 16 VGPRs.
    float4 pt0, pt1, pv0, pv1;
    {
        const float4* tb4 = (const float4*)(t + (size_t)b0 * N);
        const float4* vb4 = (const float4*)(v + (size_t)b0 * N);
        pt0 = tb4[tid]; pt1 = tb4[tid + T];
        pv0 = vb4[tid]; pv1 = vb4[tid + T];
    }

    #pragma unroll
    for (int bb = 0; bb < BPB; ++bb) {
        const int b = b0 + bb;
        const float4* r4 = (const float4*)(r + (size_t)b * M);
        float4* o4 = (float4*)(out + (size_t)b * M);

        // Queries issued first: HBM latency hides under LDS write + lut fill.
        const float4 qa = r4[tid];
        const float4 qb = r4[tid + T];

        // Commit prefetched t/v to LDS; plant sentinels; init lut (packed u32).
        ((float4*)st)[tid]     = pt0;
        ((float4*)st)[tid + T] = pt1;
        ((float4*)sv)[tid]     = pv0;
        ((float4*)sv)[tid + T] = pv1;
        if (tid < 4) st[N + tid] = FLT_MAX;
        for (int i = tid; i < K / 2; i += T)
            ((unsigned int*)lut)[i] = ((unsigned)N << 16) | (unsigned)N;

        // Issue NEXT batch's t/v loads now (regs just freed by the ds_writes):
        // they stay in flight across lut fill + this batch's whole query phase,
        // overlapping the HBM stream with the LDS-bound gather phase.
        if (bb + 1 < BPB) {
            const float4* tb4 = (const float4*)(t + (size_t)(b + 1) * N);
            const float4* vb4 = (const float4*)(v + (size_t)(b + 1) * N);
            pt0 = tb4[tid]; pt1 = tb4[tid + T];
            pv0 = vb4[tid]; pv1 = vb4[tid + T];
        }
        __syncthreads();

        // Range-fill: element j claims buckets ((int)(t[j-1]*K), (int)(t[j]*K)].
        // Disjoint ranges -> no races; u16 LDS writes are byte-enable safe.
        for (int j = tid; j < N; j += T) {
            const float tj = st[j];
            int khi = (int)(tj * (float)K);
            if (khi > K - 1) khi = K - 1;
            const int klo = (j > 0) ? (int)(st[j - 1] * (float)K) + 1 : 0;
            for (int k = klo; k <= khi; ++k) lut[k] = (unsigned short)j;
        }
        __syncthreads();

        const float tfirst = st[0];
        const float vfirst = sv[0];
        const float tlast = st[N - 1];
        const float vlast = sv[N - 1];

        float q[8] = {qa.x, qa.y, qa.z, qa.w, qb.x, qb.y, qb.z, qb.w};
        int lo[8];

        // Phase 1: all 8 lut loads issued together.
        // Invariant: t[lo-1] <= q (strict bucket math), so scan starts at lo.
        #pragma unroll
        for (int j = 0; j < 8; ++j) {
            int k = (int)(q[j] * (float)K);
            k = k < 0 ? 0 : (k > K - 1 ? K - 1 : k);
            lo[j] = lut[k];
        }
        // Phase 2: sentinel-bounded scan — no clamp, no bounds check.
        // K~N means ~1 point/bucket: 2 predicated steps, rare fallback.
        #pragma unroll
        for (int j = 0; j < 8; ++j) {
            lo[j] += (st[lo[j]] <= q[j]) ? 1 : 0;
            lo[j] += (st[lo[j]] <= q[j]) ? 1 : 0;
            while (st[lo[j]] <= q[j]) ++lo[j];
        }
        // Phase 3: final pair fetches (ds_read2_b32) + interp math (fast rcp).
        float o[8];
        #pragma unroll
        for (int j = 0; j < 8; ++j) {
            const int idx = lo[j] < 1 ? 1 : (lo[j] > N - 1 ? N - 1 : lo[j]);
            const float t0 = st[idx - 1];
            const float t1 = st[idx];
            const float v0 = sv[idx - 1];
            const float v1 = sv[idx];
            const float d = t1 - t0;
            const float rden = __builtin_amdgcn_rcpf(d == 0.0f ? 1.0f : d);
            float oo = v0 + (q[j] - t0) * rden * (v1 - v0);
            oo = (q[j] < tfirst) ? vfirst : oo;
            oo = (q[j] > tlast) ? vlast : oo;
            o[j] = oo;
        }
        o4[tid] = make_float4(o[0], o[1], o[2], o[3]);
        o4[tid + T] = make_float4(o[4], o[5], o[6], o[7]);

        // Protect LDS: next iteration's ds_writes must wait for all readers.
        if (bb + 1 < BPB) __syncthreads();
    }
}

extern "C" void kernel_launch(void* const* d_in, const int* in_sizes, int n_in,
                              void* d_out, int out_size, void* d_ws, size_t ws_size,
                              hipStream_t stream) {
    const float* t = (const float*)d_in[0];
    const float* v = (const float*)d_in[1];
    const float* r = (const float*)d_in[2];
    float* out = (float*)d_out;
    interp_kernel<<<GRID, T, 0, stream>>>(t, v, r, out);
}